// Round 3
// baseline (2431.833 us; speedup 1.0000x reference)
//
#include <hip/hip_runtime.h>
#include <math.h>

// ---- problem constants ----
// B=32, H=W=56, C=256, WS=7, SHIFT=3, HEADS=8, HD=32, HIDDEN=1024
// N=49 tokens/window, NW=64 windows/img, WT=2048 windows, T=100352 tokens
static constexpr long T_TOK = 100352;

__device__ __forceinline__ float b2f(unsigned short u) {
    return __uint_as_float(((unsigned)u) << 16);
}
__device__ __forceinline__ unsigned short f2b(float f) {
    unsigned u = __float_as_uint(f);
    u += 0x7FFFu + ((u >> 16) & 1u);     // round-to-nearest-even
    return (unsigned short)(u >> 16);
}

// ---- dtype detector: x ~ N(0,1). bf16 stream -> ~99% of uint16s decode to
// |v| in [1/64, 8]; fp32 stream read as uint16 -> ~51%. flag: 1 = fp32 inputs.
__global__ void detect_kernel(const unsigned short* __restrict__ x, int* flag) {
    __shared__ int cnt;
    if (threadIdx.x == 0) cnt = 0;
    __syncthreads();
    int local = 0;
    for (int i = 0; i < 16; ++i) {
        float a = fabsf(b2f(x[threadIdx.x * 16 + i]));
        if (a >= 0.015625f && a <= 8.0f) local++;   // NaN fails both
    }
    atomicAdd(&cnt, local);
    __syncthreads();
    if (threadIdx.x == 0) *flag = (cnt < 3072) ? 1 : 0;   // 3072/4096 = 0.75
}

// ---- normalize one param tensor to bf16 in ws ----
__global__ void conv_kernel(const void* __restrict__ src, unsigned short* __restrict__ dst,
                            int n, const int* __restrict__ flag) {
    int i = blockIdx.x * 256 + threadIdx.x;
    if (i >= n) return;
    if (*flag) dst[i] = f2b(((const float*)src)[i]);
    else       dst[i] = ((const unsigned short*)src)[i];
}

// ---------------- LayerNorm (one wave per token, 4 ch/lane) ----------------
// mode 0: LN1 -> shifted + window-partitioned layout. mode 1: LN2 -> natural.
// flagp: if non-null and *flagp, input is fp32; else bf16.
__global__ __launch_bounds__(256) void ln_kernel(
    const void* __restrict__ xin,
    const unsigned short* __restrict__ g,
    const unsigned short* __restrict__ bsh,
    unsigned short* __restrict__ out, int mode, const int* __restrict__ flagp)
{
    int lane = threadIdx.x & 63;
    int wv = threadIdx.x >> 6;
    long t = (long)blockIdx.x * 4 + wv;          // token index, < 100352
    int c0 = lane * 4;
    bool f32 = flagp && (*flagp != 0);
    float v0, v1, v2, v3;
    if (f32) {
        float4 xv = *(const float4*)((const float*)xin + t * 256 + c0);
        v0 = xv.x; v1 = xv.y; v2 = xv.z; v3 = xv.w;
    } else {
        ushort4 xv = *(const ushort4*)((const unsigned short*)xin + t * 256 + c0);
        v0 = b2f(xv.x); v1 = b2f(xv.y); v2 = b2f(xv.z); v3 = b2f(xv.w);
    }
    float s1 = v0 + v1 + v2 + v3;
    float s2 = v0*v0 + v1*v1 + v2*v2 + v3*v3;
    #pragma unroll
    for (int off = 32; off > 0; off >>= 1) {
        s1 += __shfl_down(s1, off, 64);
        s2 += __shfl_down(s2, off, 64);
    }
    s1 = __shfl(s1, 0, 64);
    s2 = __shfl(s2, 0, 64);
    float mean = s1 * (1.0f / 256.0f);
    float var  = s2 * (1.0f / 256.0f) - mean * mean;
    float rs = rsqrtf(fmaxf(var, 0.0f) + 1e-5f);
    ushort4 gv = *(const ushort4*)(g + c0);
    ushort4 bv = *(const ushort4*)(bsh + c0);
    ushort4 ov;
    ov.x = f2b((v0 - mean) * rs * b2f(gv.x) + b2f(bv.x));
    ov.y = f2b((v1 - mean) * rs * b2f(gv.y) + b2f(bv.y));
    ov.z = f2b((v2 - mean) * rs * b2f(gv.z) + b2f(bv.z));
    ov.w = f2b((v3 - mean) * rs * b2f(gv.w) + b2f(bv.w));
    long oidx;
    if (mode == 0) {
        int b_ = (int)(t / 3136);
        int hw = (int)(t % 3136);
        int hh = hw / 56, wc = hw % 56;
        int i = hh - 3; if (i < 0) i += 56;   // roll(-3)
        int j = wc - 3; if (j < 0) j += 56;
        oidx = ((long)(b_ * 64 + (i / 7) * 8 + (j / 7)) * 49
                + (i % 7) * 7 + (j % 7)) * 256 + c0;
    } else {
        oidx = t * 256 + c0;
    }
    *(ushort4*)(out + oidx) = ov;
}

// ---------------- generic 64x64-tile fp32 GEMM, bf16 A/B ----------------
// epilogue modes:
//  0 plain bf16 store (qkv)
//  1 window-reverse+roll(+3) remap, add res (=x, fp32 if *resflag) -> out
//    (out fp32 if *oflag)                                   (proj -> x2)
//  2 exact GELU, bf16 store (fc1)
//  3 add res (=x2, dtype per oflag) -> out (dtype per oflag) (fc2 -> final)
__global__ __launch_bounds__(256) void gemm64(
    const unsigned short* __restrict__ A,
    const unsigned short* __restrict__ Bw,
    const unsigned short* __restrict__ bias,
    void* __restrict__ out,
    const void* __restrict__ res,
    int M, int N, int K, int mode,
    const int* __restrict__ resflag, const int* __restrict__ oflag)
{
    __shared__ float As[16][64];   // As[k][m]
    __shared__ float Bs[16][64];   // Bs[k][n]
    int tid = threadIdx.x;
    int ty = tid >> 4, tx = tid & 15;
    long mBase = (long)blockIdx.y * 64;
    int  nBase = blockIdx.x * 64;

    int la_m = tid >> 2;           // 0..63
    int la_k = (tid & 3) * 4;      // 0,4,8,12
    int lb_k = tid >> 4;           // 0..15
    int lb_n = (tid & 15) * 4;     // 0..60

    float acc[4][4] = {};

    for (int k0 = 0; k0 < K; k0 += 16) {
        ushort4 av = *(const ushort4*)(A + (mBase + la_m) * K + (k0 + la_k));
        ushort4 bv = *(const ushort4*)(Bw + (long)(k0 + lb_k) * N + (nBase + lb_n));
        As[la_k + 0][la_m] = b2f(av.x);
        As[la_k + 1][la_m] = b2f(av.y);
        As[la_k + 2][la_m] = b2f(av.z);
        As[la_k + 3][la_m] = b2f(av.w);
        Bs[lb_k][lb_n + 0] = b2f(bv.x);
        Bs[lb_k][lb_n + 1] = b2f(bv.y);
        Bs[lb_k][lb_n + 2] = b2f(bv.z);
        Bs[lb_k][lb_n + 3] = b2f(bv.w);
        __syncthreads();
        #pragma unroll
        for (int kk = 0; kk < 16; ++kk) {
            float4 a = *(const float4*)&As[kk][ty * 4];
            float4 b = *(const float4*)&Bs[kk][tx * 4];
            float aa[4] = {a.x, a.y, a.z, a.w};
            float bb[4] = {b.x, b.y, b.z, b.w};
            #pragma unroll
            for (int i = 0; i < 4; ++i)
                #pragma unroll
                for (int j = 0; j < 4; ++j)
                    acc[i][j] += aa[i] * bb[j];
        }
        __syncthreads();
    }

    bool resf32 = resflag && (*resflag != 0);
    bool outf32 = oflag && (*oflag != 0);
    unsigned short* outb = (unsigned short*)out;
    float* outf = (float*)out;
    #pragma unroll
    for (int i = 0; i < 4; ++i) {
        long r = mBase + ty * 4 + i;
        long natRow = 0;
        if (mode == 1) {
            int w = (int)(r / 49), n = (int)(r % 49);
            int b_ = w >> 6, widx = w & 63;
            int wi = widx >> 3, wj = widx & 7;
            int pi = n / 7, pj = n % 7;
            int ii = wi * 7 + pi, jj = wj * 7 + pj;
            int h = ii + 3; if (h >= 56) h -= 56;   // roll(+3)
            int wc = jj + 3; if (wc >= 56) wc -= 56;
            natRow = ((long)b_ * 3136 + h * 56 + wc);
        }
        #pragma unroll
        for (int j = 0; j < 4; ++j) {
            int c = nBase + tx * 4 + j;
            float v = acc[i][j] + b2f(bias[c]);
            if (mode == 2) {
                v = 0.5f * v * (1.0f + erff(v * 0.70710678118654752f));
                outb[r * N + c] = f2b(v);
            } else if (mode == 0) {
                outb[r * N + c] = f2b(v);
            } else if (mode == 3) {
                long o = r * N + c;
                float rv = outf32 ? outf[o] : b2f(((const unsigned short*)res)[o]);
                v += rv;
                if (outf32) outf[o] = v; else outb[o] = f2b(v);
            } else { // mode 1
                long o = natRow * 256 + c;
                float rv = resf32 ? ((const float*)res)[o]
                                  : b2f(((const unsigned short*)res)[o]);
                v += rv;
                if (outf32) outf[o] = v; else outb[o] = f2b(v);
            }
        }
    }
}

// ---------------- attention: one block per (window, head) ----------------
__global__ __launch_bounds__(256) void attn_kernel(
    const unsigned short* __restrict__ qkv,      // [WT*49, 768]
    const unsigned short* __restrict__ rel_bias, // [169, 8] bf16
    unsigned short* __restrict__ out)            // [WT*49, 256]
{
    __shared__ float qs[49][33], ks[49][33], vs[49][33];
    __shared__ float ss[49][49];
    int w = blockIdx.x;     // 0..2047
    int h = blockIdx.y;     // 0..7
    int tid = threadIdx.x;
    long base = (long)w * 49 * 768 + h * 32;

    for (int e = tid; e < 49 * 32; e += 256) {
        int n = e >> 5, d = e & 31;
        long o = base + (long)n * 768 + d;
        qs[n][d] = b2f(qkv[o]) * 0.17677669529663687f;  // HD^-0.5
        ks[n][d] = b2f(qkv[o + 256]);
        vs[n][d] = b2f(qkv[o + 512]);
    }
    __syncthreads();

    int widx = w & 63;
    int wi = widx >> 3, wj = widx & 7;
    for (int e = tid; e < 49 * 49; e += 256) {
        int n = e / 49, m = e - n * 49;
        float s = 0.0f;
        #pragma unroll
        for (int kk = 0; kk < 32; ++kk) s += qs[n][kk] * ks[m][kk];
        int in_ = n / 7, jn = n % 7, im = m / 7, jm = m % 7;
        int ridx = (im - in_ + 6) * 13 + (jm - jn + 6);
        s += b2f(rel_bias[ridx * 8 + h]);
        int rn = wi * 7 + in_, cn = wj * 7 + jn;
        int rm = wi * 7 + im,  cm = wj * 7 + jm;
        int tn = (rn < 49 ? 0 : (rn < 53 ? 1 : 2)) * 3 + (cn < 49 ? 0 : (cn < 53 ? 1 : 2));
        int tm = (rm < 49 ? 0 : (rm < 53 ? 1 : 2)) * 3 + (cm < 49 ? 0 : (cm < 53 ? 1 : 2));
        if (tn != tm) s -= 100.0f;
        ss[n][m] = s;
    }
    __syncthreads();

    if (tid < 49) {
        float mx = -1e30f;
        for (int m = 0; m < 49; ++m) mx = fmaxf(mx, ss[tid][m]);
        float sum = 0.0f;
        for (int m = 0; m < 49; ++m) {
            float e_ = __expf(ss[tid][m] - mx);
            ss[tid][m] = e_;
            sum += e_;
        }
        float inv = 1.0f / sum;
        for (int m = 0; m < 49; ++m) ss[tid][m] *= inv;
    }
    __syncthreads();

    for (int e = tid; e < 49 * 32; e += 256) {
        int n = e >> 5, d = e & 31;
        float s = 0.0f;
        #pragma unroll
        for (int m = 0; m < 49; ++m) s += ss[n][m] * vs[m][d];
        out[((long)w * 49 + n) * 256 + h * 32 + d] = f2b(s);
    }
}

extern "C" void kernel_launch(void* const* d_in, const int* in_sizes, int n_in,
                              void* d_out, int out_size, void* d_ws, size_t ws_size,
                              hipStream_t stream) {
    (void)n_in; (void)out_size; (void)ws_size; (void)in_sizes;
    unsigned short* ws  = (unsigned short*)d_ws;
    const size_t TT = (size_t)T_TOK;

    // ws layout (bf16 elements)
    unsigned short* r0  = ws;                        // [T,256]: xw / attn_out / x2n
    unsigned short* r1  = ws + TT * 256;             // [T,1024]: qkv[T,768] then hidden
    unsigned short* pb  = ws + TT * 256 + TT * 1024; // params, bf16-normalized
    const size_t O_QKVW = 0,      O_QKVB = 196608, O_RELB = 197376, O_PROJW = 198728;
    const size_t O_PROJB = 264264, O_N1G = 264520, O_N1B = 264776;
    const size_t O_N2G = 265032,  O_N2B = 265288, O_FC1W = 265544, O_FC1B = 527688;
    const size_t O_FC2W = 528712, O_FC2B = 790856, O_PEND = 791112;
    int* flag = (int*)(pb + O_PEND);

    // 0) detect input dtype (1 = fp32, 0 = bf16); output dtype follows it
    detect_kernel<<<1, 256, 0, stream>>>((const unsigned short*)d_in[0], flag);

    // 1) normalize all params to bf16 in ws
    struct { int idx; size_t off; int n; } cv[13] = {
        {1, O_N1G, 256}, {2, O_N1B, 256}, {3, O_QKVW, 196608}, {4, O_QKVB, 768},
        {5, O_RELB, 1352}, {6, O_PROJW, 65536}, {7, O_PROJB, 256},
        {8, O_N2G, 256}, {9, O_N2B, 256}, {10, O_FC1W, 262144}, {11, O_FC1B, 1024},
        {12, O_FC2W, 262144}, {13, O_FC2B, 256},
    };
    for (int i = 0; i < 13; ++i)
        conv_kernel<<<(cv[i].n + 255) / 256, 256, 0, stream>>>(
            d_in[cv[i].idx], pb + cv[i].off, cv[i].n, flag);

    const long T = T_TOK;
    unsigned short* xw       = r0;
    unsigned short* qkv      = r1;
    unsigned short* attn_out = r0;
    unsigned short* x2n      = r0;
    unsigned short* hidden   = r1;

    // 2) LN1 + roll(-3,-3) + window partition (x dtype per flag)
    ln_kernel<<<dim3(T / 4), 256, 0, stream>>>(d_in[0], pb + O_N1G, pb + O_N1B, xw, 0, flag);
    // 3) qkv = xw @ qkv_w + qkv_b        (M=T, N=768, K=256)
    gemm64<<<dim3(12, T / 64), 256, 0, stream>>>(xw, pb + O_QKVW, pb + O_QKVB, qkv,
                                                 nullptr, (int)T, 768, 256, 0,
                                                 nullptr, nullptr);
    // 4) windowed multi-head attention
    attn_kernel<<<dim3(2048, 8), 256, 0, stream>>>(qkv, pb + O_RELB, attn_out);
    // 5) x2 = x + reverse(roll(proj(attn_out))) -> d_out (x and d_out dtype per flag)
    gemm64<<<dim3(4, T / 64), 256, 0, stream>>>(attn_out, pb + O_PROJW, pb + O_PROJB,
                                                d_out, d_in[0], (int)T, 256, 256, 1,
                                                flag, flag);
    // 6) LN2(x2) -> x2n (x2 dtype per flag)
    ln_kernel<<<dim3(T / 4), 256, 0, stream>>>(d_out, pb + O_N2G, pb + O_N2B, x2n, 1, flag);
    // 7) hidden = gelu(x2n @ fc1_w + fc1_b)      (M=T, N=1024, K=256)
    gemm64<<<dim3(16, T / 64), 256, 0, stream>>>(x2n, pb + O_FC1W, pb + O_FC1B, hidden,
                                                 nullptr, (int)T, 1024, 256, 2,
                                                 nullptr, nullptr);
    // 8) out = x2 + hidden @ fc2_w + fc2_b       (M=T, N=256, K=1024)
    gemm64<<<dim3(4, T / 64), 256, 0, stream>>>(hidden, pb + O_FC2W, pb + O_FC2B, d_out,
                                                d_out, (int)T, 256, 1024, 3,
                                                nullptr, flag);
}

// Round 4
// 1233.882 us; speedup vs baseline: 1.9709x; 1.9709x over previous
//
#include <hip/hip_runtime.h>
#include <math.h>

// ---- problem constants ----
// B=32, H=W=56, C=256, WS=7, SHIFT=3, HEADS=8, HD=32, HIDDEN=1024
// N=49 tokens/window, NW=64 windows/img, WT=2048 windows, T=100352 tokens
static constexpr long T_TOK = 100352;

typedef __attribute__((ext_vector_type(8))) short short8;
typedef __attribute__((ext_vector_type(8))) unsigned short ushort8v;
typedef __attribute__((ext_vector_type(4))) float floatx4;

__device__ __forceinline__ float b2f(unsigned short u) {
    return __uint_as_float(((unsigned)u) << 16);
}
__device__ __forceinline__ unsigned short f2b(float f) {
    unsigned u = __float_as_uint(f);
    u += 0x7FFFu + ((u >> 16) & 1u);     // round-to-nearest-even
    return (unsigned short)(u >> 16);
}

// ---- dtype detector: flag = 1 if inputs are fp32 (confirmed in R3), 0 if bf16.
__global__ void detect_kernel(const unsigned short* __restrict__ x, int* flag) {
    __shared__ int cnt;
    if (threadIdx.x == 0) cnt = 0;
    __syncthreads();
    int local = 0;
    for (int i = 0; i < 16; ++i) {
        float a = fabsf(b2f(x[threadIdx.x * 16 + i]));
        if (a >= 0.015625f && a <= 8.0f) local++;
    }
    atomicAdd(&cnt, local);
    __syncthreads();
    if (threadIdx.x == 0) *flag = (cnt < 3072) ? 1 : 0;
}

// ---- normalize a param tensor to bf16 in ws ----
__global__ void conv_kernel(const void* __restrict__ src, unsigned short* __restrict__ dst,
                            int n, const int* __restrict__ flag) {
    int i = blockIdx.x * 256 + threadIdx.x;
    if (i >= n) return;
    if (*flag) dst[i] = f2b(((const float*)src)[i]);
    else       dst[i] = ((const unsigned short*)src)[i];
}

// ---- normalize + transpose weight [K][N] -> bf16 [N][K] ----
__global__ void convT_kernel(const void* __restrict__ src, unsigned short* __restrict__ dst,
                             int K, int N, const int* __restrict__ flag) {
    int i = blockIdx.x * 256 + threadIdx.x;
    if (i >= K * N) return;
    int k = i / N, n = i - k * N;
    unsigned short v = (*flag) ? f2b(((const float*)src)[i])
                               : ((const unsigned short*)src)[i];
    dst[(long)n * K + k] = v;
}

// ---------------- LayerNorm (one wave per token, 4 ch/lane) ----------------
__global__ __launch_bounds__(256) void ln_kernel(
    const void* __restrict__ xin,
    const unsigned short* __restrict__ g,
    const unsigned short* __restrict__ bsh,
    unsigned short* __restrict__ out, int mode, const int* __restrict__ flagp)
{
    int lane = threadIdx.x & 63;
    int wv = threadIdx.x >> 6;
    long t = (long)blockIdx.x * 4 + wv;
    int c0 = lane * 4;
    bool f32 = flagp && (*flagp != 0);
    float v0, v1, v2, v3;
    if (f32) {
        float4 xv = *(const float4*)((const float*)xin + t * 256 + c0);
        v0 = xv.x; v1 = xv.y; v2 = xv.z; v3 = xv.w;
    } else {
        ushort4 xv = *(const ushort4*)((const unsigned short*)xin + t * 256 + c0);
        v0 = b2f(xv.x); v1 = b2f(xv.y); v2 = b2f(xv.z); v3 = b2f(xv.w);
    }
    float s1 = v0 + v1 + v2 + v3;
    float s2 = v0*v0 + v1*v1 + v2*v2 + v3*v3;
    #pragma unroll
    for (int off = 32; off > 0; off >>= 1) {
        s1 += __shfl_down(s1, off, 64);
        s2 += __shfl_down(s2, off, 64);
    }
    s1 = __shfl(s1, 0, 64);
    s2 = __shfl(s2, 0, 64);
    float mean = s1 * (1.0f / 256.0f);
    float var  = s2 * (1.0f / 256.0f) - mean * mean;
    float rs = rsqrtf(fmaxf(var, 0.0f) + 1e-5f);
    ushort4 gv = *(const ushort4*)(g + c0);
    ushort4 bv = *(const ushort4*)(bsh + c0);
    ushort4 ov;
    ov.x = f2b((v0 - mean) * rs * b2f(gv.x) + b2f(bv.x));
    ov.y = f2b((v1 - mean) * rs * b2f(gv.y) + b2f(bv.y));
    ov.z = f2b((v2 - mean) * rs * b2f(gv.z) + b2f(bv.z));
    ov.w = f2b((v3 - mean) * rs * b2f(gv.w) + b2f(bv.w));
    long oidx;
    if (mode == 0) {
        int b_ = (int)(t / 3136);
        int hw = (int)(t % 3136);
        int hh = hw / 56, wc = hw % 56;
        int i = hh - 3; if (i < 0) i += 56;   // roll(-3)
        int j = wc - 3; if (j < 0) j += 56;
        oidx = ((long)(b_ * 64 + (i / 7) * 8 + (j / 7)) * 49
                + (i % 7) * 7 + (j % 7)) * 256 + c0;
    } else {
        oidx = t * 256 + c0;
    }
    *(ushort4*)(out + oidx) = ov;
}

// ------------- MFMA GEMM: 128x128 tile, 4 waves, bf16 in, fp32 acc -------------
// A [M][K] bf16, Bt [N][K] bf16 (pre-transposed weights). Epilogue modes:
//  0 plain bf16 (qkv) | 1 window-reverse+roll(+3) remap, +res -> out (dtypes per
//  flags) (proj) | 2 exact GELU bf16 (fc1) | 3 +res(=out) -> out (fc2)
__global__ __launch_bounds__(256) void gemm_mfma(
    const unsigned short* __restrict__ A,
    const unsigned short* __restrict__ Bt,
    const unsigned short* __restrict__ bias,
    void* __restrict__ out,
    const void* __restrict__ res,
    int M, int N, int K, int mode,
    const int* __restrict__ resflag, const int* __restrict__ oflag)
{
    __shared__ __align__(16) unsigned short As[128][56];  // row pad 56: 112B rows,
    __shared__ __align__(16) unsigned short Bs[128][56];  // 16B-aligned, 2-way banks
    const int tid  = threadIdx.x;
    const int lane = tid & 63, wave = tid >> 6;
    const int q = lane >> 4, l16 = lane & 15;
    const int wm = wave >> 1, wn = wave & 1;
    const long m0 = (long)blockIdx.y * 128;
    const int  n0 = blockIdx.x * 128;
    const int sr = tid >> 1;           // staging row 0..127
    const int sc = (tid & 1) * 16;     // k-offset (16 bf16 = 32B)

    floatx4 acc[4][4];
    #pragma unroll
    for (int i = 0; i < 4; ++i)
        #pragma unroll
        for (int j = 0; j < 4; ++j)
            acc[i][j] = (floatx4){0.f, 0.f, 0.f, 0.f};

    const unsigned short* Ap = A  + (m0 + sr) * (long)K + sc;
    const unsigned short* Bp = Bt + ((long)(n0 + sr)) * K + sc;

    for (int k0 = 0; k0 < K; k0 += 32) {
        ushort8v a0 = *(const ushort8v*)(Ap + k0);
        ushort8v a1 = *(const ushort8v*)(Ap + k0 + 8);
        ushort8v b0 = *(const ushort8v*)(Bp + k0);
        ushort8v b1 = *(const ushort8v*)(Bp + k0 + 8);
        __syncthreads();                       // prev-iter LDS reads done
        *(ushort8v*)&As[sr][sc]     = a0;
        *(ushort8v*)&As[sr][sc + 8] = a1;
        *(ushort8v*)&Bs[sr][sc]     = b0;
        *(ushort8v*)&Bs[sr][sc + 8] = b1;
        __syncthreads();
        short8 af[4], bfr[4];
        #pragma unroll
        for (int i = 0; i < 4; ++i)
            af[i] = *(const short8*)&As[wm * 64 + i * 16 + l16][q * 8];
        #pragma unroll
        for (int j = 0; j < 4; ++j)
            bfr[j] = *(const short8*)&Bs[wn * 64 + j * 16 + l16][q * 8];
        #pragma unroll
        for (int i = 0; i < 4; ++i)
            #pragma unroll
            for (int j = 0; j < 4; ++j)
                acc[i][j] = __builtin_amdgcn_mfma_f32_16x16x32_bf16(
                    af[i], bfr[j], acc[i][j], 0, 0, 0);
    }

    const bool resf32 = resflag && (*resflag != 0);
    const bool outf32 = oflag && (*oflag != 0);
    unsigned short* outb = (unsigned short*)out;
    float* outf = (float*)out;
    #pragma unroll
    for (int i = 0; i < 4; ++i) {
        #pragma unroll
        for (int r = 0; r < 4; ++r) {
            long grow = m0 + wm * 64 + i * 16 + q * 4 + r;  // C/D: row=quad*4+reg
            long natRow = 0;
            if (mode == 1) {
                int w = (int)(grow / 49), n = (int)(grow % 49);
                int b_ = w >> 6, widx = w & 63;
                int wi = widx >> 3, wj = widx & 7;
                int pi = n / 7, pj = n % 7;
                int ii = wi * 7 + pi, jj = wj * 7 + pj;
                int h = ii + 3; if (h >= 56) h -= 56;   // roll(+3)
                int wc = jj + 3; if (wc >= 56) wc -= 56;
                natRow = ((long)b_ * 3136 + h * 56 + wc);
            }
            #pragma unroll
            for (int j = 0; j < 4; ++j) {
                int gcol = n0 + wn * 64 + j * 16 + l16;     // C/D: col=lane&15
                float v = acc[i][j][r] + b2f(bias[gcol]);
                if (mode == 2) {
                    v = 0.5f * v * (1.0f + erff(v * 0.70710678118654752f));
                    outb[grow * N + gcol] = f2b(v);
                } else if (mode == 0) {
                    outb[grow * N + gcol] = f2b(v);
                } else if (mode == 3) {
                    long o = grow * N + gcol;
                    float rv = outf32 ? outf[o] : b2f(((const unsigned short*)res)[o]);
                    v += rv;
                    if (outf32) outf[o] = v; else outb[o] = f2b(v);
                } else { // mode 1
                    long o = natRow * 256 + gcol;
                    float rv = resf32 ? ((const float*)res)[o]
                                      : b2f(((const unsigned short*)res)[o]);
                    v += rv;
                    if (outf32) outf[o] = v; else outb[o] = f2b(v);
                }
            }
        }
    }
}

// ---------------- attention: one block per (window, head) ----------------
__global__ __launch_bounds__(256) void attn_kernel(
    const unsigned short* __restrict__ qkv,      // [WT*49, 768]
    const unsigned short* __restrict__ rel_bias, // [169, 8] bf16
    unsigned short* __restrict__ out)            // [WT*49, 256]
{
    __shared__ float qs[49][33], ks[49][33], vs[49][33];
    __shared__ float ss[49][49];
    int w = blockIdx.x;
    int h = blockIdx.y;
    int tid = threadIdx.x;
    long base = (long)w * 49 * 768 + h * 32;

    for (int e = tid; e < 49 * 32; e += 256) {
        int n = e >> 5, d = e & 31;
        long o = base + (long)n * 768 + d;
        qs[n][d] = b2f(qkv[o]) * 0.17677669529663687f;  // HD^-0.5
        ks[n][d] = b2f(qkv[o + 256]);
        vs[n][d] = b2f(qkv[o + 512]);
    }
    __syncthreads();

    int widx = w & 63;
    int wi = widx >> 3, wj = widx & 7;
    for (int e = tid; e < 49 * 49; e += 256) {
        int n = e / 49, m = e - n * 49;
        float s = 0.0f;
        #pragma unroll
        for (int kk = 0; kk < 32; ++kk) s += qs[n][kk] * ks[m][kk];
        int in_ = n / 7, jn = n % 7, im = m / 7, jm = m % 7;
        int ridx = (im - in_ + 6) * 13 + (jm - jn + 6);
        s += b2f(rel_bias[ridx * 8 + h]);
        int rn = wi * 7 + in_, cn = wj * 7 + jn;
        int rm = wi * 7 + im,  cm = wj * 7 + jm;
        int tn = (rn < 49 ? 0 : (rn < 53 ? 1 : 2)) * 3 + (cn < 49 ? 0 : (cn < 53 ? 1 : 2));
        int tm = (rm < 49 ? 0 : (rm < 53 ? 1 : 2)) * 3 + (cm < 49 ? 0 : (cm < 53 ? 1 : 2));
        if (tn != tm) s -= 100.0f;
        ss[n][m] = s;
    }
    __syncthreads();

    if (tid < 49) {
        float mx = -1e30f;
        for (int m = 0; m < 49; ++m) mx = fmaxf(mx, ss[tid][m]);
        float sum = 0.0f;
        for (int m = 0; m < 49; ++m) {
            float e_ = __expf(ss[tid][m] - mx);
            ss[tid][m] = e_;
            sum += e_;
        }
        float inv = 1.0f / sum;
        for (int m = 0; m < 49; ++m) ss[tid][m] *= inv;
    }
    __syncthreads();

    for (int e = tid; e < 49 * 32; e += 256) {
        int n = e >> 5, d = e & 31;
        float s = 0.0f;
        #pragma unroll
        for (int m = 0; m < 49; ++m) s += ss[n][m] * vs[m][d];
        out[((long)w * 49 + n) * 256 + h * 32 + d] = f2b(s);
    }
}

extern "C" void kernel_launch(void* const* d_in, const int* in_sizes, int n_in,
                              void* d_out, int out_size, void* d_ws, size_t ws_size,
                              hipStream_t stream) {
    (void)n_in; (void)out_size; (void)ws_size; (void)in_sizes;
    unsigned short* ws  = (unsigned short*)d_ws;
    const size_t TT = (size_t)T_TOK;

    unsigned short* r0  = ws;                        // [T,256]: xw / attn_out / x2n
    unsigned short* r1  = ws + TT * 256;             // [T,1024]: qkv then hidden
    unsigned short* pb  = ws + TT * 256 + TT * 1024; // params (weights transposed)
    const size_t O_QKVW = 0,      O_QKVB = 196608, O_RELB = 197376, O_PROJW = 198728;
    const size_t O_PROJB = 264264, O_N1G = 264520, O_N1B = 264776;
    const size_t O_N2G = 265032,  O_N2B = 265288, O_FC1W = 265544, O_FC1B = 527688;
    const size_t O_FC2W = 528712, O_FC2B = 790856, O_PEND = 791112;
    int* flag = (int*)(pb + O_PEND);

    // 0) detect input dtype (1 = fp32; confirmed fp32 in R3, kept dynamic)
    detect_kernel<<<1, 256, 0, stream>>>((const unsigned short*)d_in[0], flag);

    // 1) params -> bf16; weights transposed to [N][K]
    struct { int idx; size_t off; int n; } cv[9] = {
        {1, O_N1G, 256}, {2, O_N1B, 256}, {4, O_QKVB, 768},
        {5, O_RELB, 1352}, {7, O_PROJB, 256},
        {8, O_N2G, 256}, {9, O_N2B, 256}, {11, O_FC1B, 1024}, {13, O_FC2B, 256},
    };
    for (int i = 0; i < 9; ++i)
        conv_kernel<<<(cv[i].n + 255) / 256, 256, 0, stream>>>(
            d_in[cv[i].idx], pb + cv[i].off, cv[i].n, flag);
    convT_kernel<<<(196608 + 255) / 256, 256, 0, stream>>>(d_in[3],  pb + O_QKVW, 256, 768,  flag);
    convT_kernel<<<(65536  + 255) / 256, 256, 0, stream>>>(d_in[6],  pb + O_PROJW, 256, 256, flag);
    convT_kernel<<<(262144 + 255) / 256, 256, 0, stream>>>(d_in[10], pb + O_FC1W, 256, 1024, flag);
    convT_kernel<<<(262144 + 255) / 256, 256, 0, stream>>>(d_in[12], pb + O_FC2W, 1024, 256, flag);

    const long T = T_TOK;
    unsigned short* xw       = r0;
    unsigned short* qkv      = r1;
    unsigned short* attn_out = r0;
    unsigned short* x2n      = r0;
    unsigned short* hidden   = r1;

    // 2) LN1 + roll(-3,-3) + window partition
    ln_kernel<<<dim3(T / 4), 256, 0, stream>>>(d_in[0], pb + O_N1G, pb + O_N1B, xw, 0, flag);
    // 3) qkv = xw @ qkv_w + qkv_b        (M=T, N=768, K=256)
    gemm_mfma<<<dim3(6, T / 128), 256, 0, stream>>>(xw, pb + O_QKVW, pb + O_QKVB, qkv,
                                                    nullptr, (int)T, 768, 256, 0,
                                                    nullptr, nullptr);
    // 4) windowed multi-head attention
    attn_kernel<<<dim3(2048, 8), 256, 0, stream>>>(qkv, pb + O_RELB, attn_out);
    // 5) x2 = x + reverse(roll(proj(attn_out))) -> d_out (fp32 per flag)
    gemm_mfma<<<dim3(2, T / 128), 256, 0, stream>>>(attn_out, pb + O_PROJW, pb + O_PROJB,
                                                    d_out, d_in[0], (int)T, 256, 256, 1,
                                                    flag, flag);
    // 6) LN2(x2) -> x2n
    ln_kernel<<<dim3(T / 4), 256, 0, stream>>>(d_out, pb + O_N2G, pb + O_N2B, x2n, 1, flag);
    // 7) hidden = gelu(x2n @ fc1_w + fc1_b)      (M=T, N=1024, K=256)
    gemm_mfma<<<dim3(8, T / 128), 256, 0, stream>>>(x2n, pb + O_FC1W, pb + O_FC1B, hidden,
                                                    nullptr, (int)T, 1024, 256, 2,
                                                    nullptr, nullptr);
    // 8) out = x2 + hidden @ fc2_w + fc2_b       (M=T, N=256, K=1024)
    gemm_mfma<<<dim3(2, T / 128), 256, 0, stream>>>(hidden, pb + O_FC2W, pb + O_FC2B, d_out,
                                                    d_out, (int)T, 256, 1024, 3,
                                                    nullptr, flag);
}

// Round 5
// 1132.059 us; speedup vs baseline: 2.1482x; 1.0899x over previous
//
#include <hip/hip_runtime.h>
#include <math.h>

// ---- problem constants ----
// B=32, H=W=56, C=256, WS=7, SHIFT=3, HEADS=8, HD=32, HIDDEN=1024
// N=49 tokens/window, NW=64 windows/img, WT=2048 windows, T=100352 tokens
static constexpr long T_TOK = 100352;

typedef __attribute__((ext_vector_type(8))) short short8;
typedef __attribute__((ext_vector_type(8))) unsigned short ushort8v;
typedef __attribute__((ext_vector_type(4))) float floatx4;

__device__ __forceinline__ float b2f(unsigned short u) {
    return __uint_as_float(((unsigned)u) << 16);
}
__device__ __forceinline__ unsigned short f2b(float f) {
    unsigned u = __float_as_uint(f);
    u += 0x7FFFu + ((u >> 16) & 1u);     // round-to-nearest-even
    return (unsigned short)(u >> 16);
}

// ---- dtype detector: flag = 1 if inputs are fp32 (confirmed), 0 if bf16.
__global__ void detect_kernel(const unsigned short* __restrict__ x, int* flag) {
    __shared__ int cnt;
    if (threadIdx.x == 0) cnt = 0;
    __syncthreads();
    int local = 0;
    for (int i = 0; i < 16; ++i) {
        float a = fabsf(b2f(x[threadIdx.x * 16 + i]));
        if (a >= 0.015625f && a <= 8.0f) local++;
    }
    atomicAdd(&cnt, local);
    __syncthreads();
    if (threadIdx.x == 0) *flag = (cnt < 3072) ? 1 : 0;
}

// ---- normalize a param tensor to bf16 in ws ----
__global__ void conv_kernel(const void* __restrict__ src, unsigned short* __restrict__ dst,
                            int n, const int* __restrict__ flag) {
    int i = blockIdx.x * 256 + threadIdx.x;
    if (i >= n) return;
    if (*flag) dst[i] = f2b(((const float*)src)[i]);
    else       dst[i] = ((const unsigned short*)src)[i];
}

// ---- normalize + transpose weight [K][N] -> bf16 [N][K] ----
__global__ void convT_kernel(const void* __restrict__ src, unsigned short* __restrict__ dst,
                             int K, int N, const int* __restrict__ flag) {
    int i = blockIdx.x * 256 + threadIdx.x;
    if (i >= K * N) return;
    int k = i / N, n = i - k * N;
    unsigned short v = (*flag) ? f2b(((const float*)src)[i])
                               : ((const unsigned short*)src)[i];
    dst[(long)n * K + k] = v;
}

// ---------------- LayerNorm (one wave per token, 4 ch/lane) ----------------
__global__ __launch_bounds__(256) void ln_kernel(
    const void* __restrict__ xin,
    const unsigned short* __restrict__ g,
    const unsigned short* __restrict__ bsh,
    unsigned short* __restrict__ out, int mode, const int* __restrict__ flagp)
{
    int lane = threadIdx.x & 63;
    int wv = threadIdx.x >> 6;
    long t = (long)blockIdx.x * 4 + wv;
    int c0 = lane * 4;
    bool f32 = flagp && (*flagp != 0);
    float v0, v1, v2, v3;
    if (f32) {
        float4 xv = *(const float4*)((const float*)xin + t * 256 + c0);
        v0 = xv.x; v1 = xv.y; v2 = xv.z; v3 = xv.w;
    } else {
        ushort4 xv = *(const ushort4*)((const unsigned short*)xin + t * 256 + c0);
        v0 = b2f(xv.x); v1 = b2f(xv.y); v2 = b2f(xv.z); v3 = b2f(xv.w);
    }
    float s1 = v0 + v1 + v2 + v3;
    float s2 = v0*v0 + v1*v1 + v2*v2 + v3*v3;
    #pragma unroll
    for (int off = 32; off > 0; off >>= 1) {
        s1 += __shfl_down(s1, off, 64);
        s2 += __shfl_down(s2, off, 64);
    }
    s1 = __shfl(s1, 0, 64);
    s2 = __shfl(s2, 0, 64);
    float mean = s1 * (1.0f / 256.0f);
    float var  = s2 * (1.0f / 256.0f) - mean * mean;
    float rs = rsqrtf(fmaxf(var, 0.0f) + 1e-5f);
    ushort4 gv = *(const ushort4*)(g + c0);
    ushort4 bv = *(const ushort4*)(bsh + c0);
    ushort4 ov;
    ov.x = f2b((v0 - mean) * rs * b2f(gv.x) + b2f(bv.x));
    ov.y = f2b((v1 - mean) * rs * b2f(gv.y) + b2f(bv.y));
    ov.z = f2b((v2 - mean) * rs * b2f(gv.z) + b2f(bv.z));
    ov.w = f2b((v3 - mean) * rs * b2f(gv.w) + b2f(bv.w));
    long oidx;
    if (mode == 0) {
        int b_ = (int)(t / 3136);
        int hw = (int)(t % 3136);
        int hh = hw / 56, wc = hw % 56;
        int i = hh - 3; if (i < 0) i += 56;   // roll(-3)
        int j = wc - 3; if (j < 0) j += 56;
        oidx = ((long)(b_ * 64 + (i / 7) * 8 + (j / 7)) * 49
                + (i % 7) * 7 + (j % 7)) * 256 + c0;
    } else {
        oidx = t * 256 + c0;
    }
    *(ushort4*)(out + oidx) = ov;
}

// ------------- MFMA GEMM: 128x128 tile, 4 waves, bf16 in, fp32 acc -------------
__global__ __launch_bounds__(256) void gemm_mfma(
    const unsigned short* __restrict__ A,
    const unsigned short* __restrict__ Bt,
    const unsigned short* __restrict__ bias,
    void* __restrict__ out,
    const void* __restrict__ res,
    int M, int N, int K, int mode,
    const int* __restrict__ resflag, const int* __restrict__ oflag)
{
    __shared__ __align__(16) unsigned short As[128][56];
    __shared__ __align__(16) unsigned short Bs[128][56];
    const int tid  = threadIdx.x;
    const int lane = tid & 63, wave = tid >> 6;
    const int q = lane >> 4, l16 = lane & 15;
    const int wm = wave >> 1, wn = wave & 1;
    const long m0 = (long)blockIdx.y * 128;
    const int  n0 = blockIdx.x * 128;
    const int sr = tid >> 1;
    const int sc = (tid & 1) * 16;

    floatx4 acc[4][4];
    #pragma unroll
    for (int i = 0; i < 4; ++i)
        #pragma unroll
        for (int j = 0; j < 4; ++j)
            acc[i][j] = (floatx4){0.f, 0.f, 0.f, 0.f};

    const unsigned short* Ap = A  + (m0 + sr) * (long)K + sc;
    const unsigned short* Bp = Bt + ((long)(n0 + sr)) * K + sc;

    for (int k0 = 0; k0 < K; k0 += 32) {
        ushort8v a0 = *(const ushort8v*)(Ap + k0);
        ushort8v a1 = *(const ushort8v*)(Ap + k0 + 8);
        ushort8v b0 = *(const ushort8v*)(Bp + k0);
        ushort8v b1 = *(const ushort8v*)(Bp + k0 + 8);
        __syncthreads();
        *(ushort8v*)&As[sr][sc]     = a0;
        *(ushort8v*)&As[sr][sc + 8] = a1;
        *(ushort8v*)&Bs[sr][sc]     = b0;
        *(ushort8v*)&Bs[sr][sc + 8] = b1;
        __syncthreads();
        short8 af[4], bfr[4];
        #pragma unroll
        for (int i = 0; i < 4; ++i)
            af[i] = *(const short8*)&As[wm * 64 + i * 16 + l16][q * 8];
        #pragma unroll
        for (int j = 0; j < 4; ++j)
            bfr[j] = *(const short8*)&Bs[wn * 64 + j * 16 + l16][q * 8];
        #pragma unroll
        for (int i = 0; i < 4; ++i)
            #pragma unroll
            for (int j = 0; j < 4; ++j)
                acc[i][j] = __builtin_amdgcn_mfma_f32_16x16x32_bf16(
                    af[i], bfr[j], acc[i][j], 0, 0, 0);
    }

    const bool resf32 = resflag && (*resflag != 0);
    const bool outf32 = oflag && (*oflag != 0);
    unsigned short* outb = (unsigned short*)out;
    float* outf = (float*)out;
    #pragma unroll
    for (int i = 0; i < 4; ++i) {
        #pragma unroll
        for (int r = 0; r < 4; ++r) {
            long grow = m0 + wm * 64 + i * 16 + q * 4 + r;
            long natRow = 0;
            if (mode == 1) {
                int w = (int)(grow / 49), n = (int)(grow % 49);
                int b_ = w >> 6, widx = w & 63;
                int wi = widx >> 3, wj = widx & 7;
                int pi = n / 7, pj = n % 7;
                int ii = wi * 7 + pi, jj = wj * 7 + pj;
                int h = ii + 3; if (h >= 56) h -= 56;
                int wc = jj + 3; if (wc >= 56) wc -= 56;
                natRow = ((long)b_ * 3136 + h * 56 + wc);
            }
            #pragma unroll
            for (int j = 0; j < 4; ++j) {
                int gcol = n0 + wn * 64 + j * 16 + l16;
                float v = acc[i][j][r] + b2f(bias[gcol]);
                if (mode == 2) {
                    v = 0.5f * v * (1.0f + erff(v * 0.70710678118654752f));
                    outb[grow * N + gcol] = f2b(v);
                } else if (mode == 0) {
                    outb[grow * N + gcol] = f2b(v);
                } else if (mode == 3) {
                    long o = grow * N + gcol;
                    float rv = outf32 ? outf[o] : b2f(((const unsigned short*)res)[o]);
                    v += rv;
                    if (outf32) outf[o] = v; else outb[o] = f2b(v);
                } else { // mode 1
                    long o = natRow * 256 + gcol;
                    float rv = resf32 ? ((const float*)res)[o]
                                      : b2f(((const unsigned short*)res)[o]);
                    v += rv;
                    if (outf32) outf[o] = v; else outb[o] = f2b(v);
                }
            }
        }
    }
}

// ---------------- MFMA attention: one wave per (window, head) ----------------
// 49 -> padded 64. QK^T: 4x4 tiles of 16x16x32 (HD=32 = one K-step).
// Softmax in registers (row = 16 lanes x 4 regs, shfl_xor<16 stays in quad group).
// P: LDS round-trip C-layout -> [query][key] rows (stride 72 = 16B-aligned).
// V: staged transposed [d][key] (zero-padded past 49) as PV B-operand.
__global__ __launch_bounds__(256) void attn_mfma(
    const unsigned short* __restrict__ qkv,      // [WT*49, 768] bf16
    const unsigned short* __restrict__ rel_bias, // [169, 8] bf16
    unsigned short* __restrict__ out)            // [WT*49, 256] bf16
{
    __shared__ __align__(16) unsigned short bias_s[1360];
    __shared__ __align__(16) unsigned short Vt[4][32][72];
    __shared__ __align__(16) unsigned short Ps[4][64][72];
    const int tid = threadIdx.x;
    const int lane = tid & 63, wave = tid >> 6;
    const int q = lane >> 4, l16 = lane & 15;
    const int unit = blockIdx.x * 4 + wave;      // 0..16383
    const int w = unit >> 3, h = unit & 7;
    const int widx = w & 63, wi = widx >> 3, wj = widx & 7;

    for (int e = tid; e < 1352; e += 256) bias_s[e] = rel_bias[e];

    // stage V^T: Vt[d][key] = V[key][d]; zero for key >= 49 (LDS is uninit!)
    const long vbase = (long)w * 49 * 768 + 512 + h * 32;
    #pragma unroll 4
    for (int it = 0; it < 32; ++it) {
        int idx = it * 64 + lane;                // 0..2047
        int key = idx >> 5, d = idx & 31;
        unsigned short v = (key < 49) ? qkv[vbase + (long)key * 768 + d]
                                      : (unsigned short)0;
        Vt[wave][d][key] = v;
    }
    __syncthreads();

    // Q/K fragments straight from global (rows clamped to 48)
    const long qbase = (long)w * 49 * 768 + h * 32;
    short8 qf[4], kf[4];
    #pragma unroll
    for (int i = 0; i < 4; ++i) {
        int qr = l16 + 16 * i; if (qr > 48) qr = 48;
        qf[i] = *(const short8*)(qkv + qbase + (long)qr * 768 + q * 8);
    }
    #pragma unroll
    for (int j = 0; j < 4; ++j) {
        int kr = l16 + 16 * j; if (kr > 48) kr = 48;
        kf[j] = *(const short8*)(qkv + qbase + 256 + (long)kr * 768 + q * 8);
    }

    // scores: S[query][key], C-layout row=q*4+r(+16i), col=l16(+16j)
    floatx4 sc[4][4];
    #pragma unroll
    for (int i = 0; i < 4; ++i)
        #pragma unroll
        for (int j = 0; j < 4; ++j)
            sc[i][j] = __builtin_amdgcn_mfma_f32_16x16x32_bf16(
                qf[i], kf[j], (floatx4){0.f, 0.f, 0.f, 0.f}, 0, 0, 0);

    // key-side precompute (depends on j,l16 only)
    int imj[4], jmj[4], tmj[4], validj[4];
    #pragma unroll
    for (int j = 0; j < 4; ++j) {
        int key = 16 * j + l16;
        validj[j] = key < 49;
        int k2 = validj[j] ? key : 48;
        int im = k2 / 7, jm = k2 - im * 7;
        imj[j] = im; jmj[j] = jm;
        int rm = wi * 7 + im, cm = wj * 7 + jm;
        tmj[j] = (rm < 49 ? 0 : (rm < 53 ? 1 : 2)) * 3
               + (cm < 49 ? 0 : (cm < 53 ? 1 : 2));
    }

    const float scale = 0.17677669529663687f;    // HD^-0.5
    #pragma unroll
    for (int i = 0; i < 4; ++i) {
        #pragma unroll
        for (int r = 0; r < 4; ++r) {
            int query = 16 * i + 4 * q + r;
            int qn = query > 48 ? 48 : query;
            int in_ = qn / 7, jn = qn - in_ * 7;
            int rn = wi * 7 + in_, cn = wj * 7 + jn;
            int tn = (rn < 49 ? 0 : (rn < 53 ? 1 : 2)) * 3
                   + (cn < 49 ? 0 : (cn < 53 ? 1 : 2));
            float sv[4];
            float mx = -1e30f;
            #pragma unroll
            for (int j = 0; j < 4; ++j) {
                float s = sc[i][j][r] * scale;
                int ridx = (imj[j] - in_ + 6) * 13 + (jmj[j] - jn + 6);
                s += b2f(bias_s[ridx * 8 + h]);
                if (tmj[j] != tn) s -= 100.0f;
                if (!validj[j]) s = -1e30f;
                sv[j] = s;
                mx = fmaxf(mx, s);
            }
            #pragma unroll
            for (int m = 1; m < 16; m <<= 1)
                mx = fmaxf(mx, __shfl_xor(mx, m, 64));
            float sum = 0.0f;
            #pragma unroll
            for (int j = 0; j < 4; ++j) { sv[j] = __expf(sv[j] - mx); sum += sv[j]; }
            #pragma unroll
            for (int m = 1; m < 16; m <<= 1)
                sum += __shfl_xor(sum, m, 64);
            float inv = 1.0f / sum;
            #pragma unroll
            for (int j = 0; j < 4; ++j)
                Ps[wave][query][16 * j + l16] = f2b(sv[j] * inv);
        }
    }
    // wave-local LDS: compiler inserts lgkmcnt waits; no barrier needed.

    // PV: O[query][d] = P @ V. A=P from Ps rows, B=V from Vt rows.
    floatx4 oacc[4][2];
    #pragma unroll
    for (int i = 0; i < 4; ++i)
        #pragma unroll
        for (int jd = 0; jd < 2; ++jd)
            oacc[i][jd] = (floatx4){0.f, 0.f, 0.f, 0.f};
    #pragma unroll
    for (int s = 0; s < 2; ++s) {
        short8 vfr[2];
        #pragma unroll
        for (int jd = 0; jd < 2; ++jd)
            vfr[jd] = *(const short8*)&Vt[wave][l16 + 16 * jd][32 * s + q * 8];
        #pragma unroll
        for (int i = 0; i < 4; ++i) {
            short8 pfr = *(const short8*)&Ps[wave][l16 + 16 * i][32 * s + q * 8];
            #pragma unroll
            for (int jd = 0; jd < 2; ++jd)
                oacc[i][jd] = __builtin_amdgcn_mfma_f32_16x16x32_bf16(
                    pfr, vfr[jd], oacc[i][jd], 0, 0, 0);
        }
    }

    const long obase = (long)w * 49 * 256 + h * 32;
    #pragma unroll
    for (int i = 0; i < 4; ++i) {
        #pragma unroll
        for (int r = 0; r < 4; ++r) {
            int query = 16 * i + 4 * q + r;
            if (query < 49) {
                #pragma unroll
                for (int jd = 0; jd < 2; ++jd)
                    out[obase + (long)query * 256 + 16 * jd + l16] =
                        f2b(oacc[i][jd][r]);
            }
        }
    }
}

extern "C" void kernel_launch(void* const* d_in, const int* in_sizes, int n_in,
                              void* d_out, int out_size, void* d_ws, size_t ws_size,
                              hipStream_t stream) {
    (void)n_in; (void)out_size; (void)ws_size; (void)in_sizes;
    unsigned short* ws  = (unsigned short*)d_ws;
    const size_t TT = (size_t)T_TOK;

    unsigned short* r0  = ws;                        // [T,256]: xw / attn_out / x2n
    unsigned short* r1  = ws + TT * 256;             // [T,1024]: qkv then hidden
    unsigned short* pb  = ws + TT * 256 + TT * 1024; // params (weights transposed)
    const size_t O_QKVW = 0,      O_QKVB = 196608, O_RELB = 197376, O_PROJW = 198728;
    const size_t O_PROJB = 264264, O_N1G = 264520, O_N1B = 264776;
    const size_t O_N2G = 265032,  O_N2B = 265288, O_FC1W = 265544, O_FC1B = 527688;
    const size_t O_FC2W = 528712, O_FC2B = 790856, O_PEND = 791112;
    int* flag = (int*)(pb + O_PEND);

    detect_kernel<<<1, 256, 0, stream>>>((const unsigned short*)d_in[0], flag);

    struct { int idx; size_t off; int n; } cv[9] = {
        {1, O_N1G, 256}, {2, O_N1B, 256}, {4, O_QKVB, 768},
        {5, O_RELB, 1352}, {7, O_PROJB, 256},
        {8, O_N2G, 256}, {9, O_N2B, 256}, {11, O_FC1B, 1024}, {13, O_FC2B, 256},
    };
    for (int i = 0; i < 9; ++i)
        conv_kernel<<<(cv[i].n + 255) / 256, 256, 0, stream>>>(
            d_in[cv[i].idx], pb + cv[i].off, cv[i].n, flag);
    convT_kernel<<<(196608 + 255) / 256, 256, 0, stream>>>(d_in[3],  pb + O_QKVW, 256, 768,  flag);
    convT_kernel<<<(65536  + 255) / 256, 256, 0, stream>>>(d_in[6],  pb + O_PROJW, 256, 256, flag);
    convT_kernel<<<(262144 + 255) / 256, 256, 0, stream>>>(d_in[10], pb + O_FC1W, 256, 1024, flag);
    convT_kernel<<<(262144 + 255) / 256, 256, 0, stream>>>(d_in[12], pb + O_FC2W, 1024, 256, flag);

    const long T = T_TOK;
    unsigned short* xw       = r0;
    unsigned short* qkv      = r1;
    unsigned short* attn_out = r0;
    unsigned short* x2n      = r0;
    unsigned short* hidden   = r1;

    // LN1 + roll(-3,-3) + window partition
    ln_kernel<<<dim3(T / 4), 256, 0, stream>>>(d_in[0], pb + O_N1G, pb + O_N1B, xw, 0, flag);
    // qkv = xw @ qkv_w + qkv_b
    gemm_mfma<<<dim3(6, T / 128), 256, 0, stream>>>(xw, pb + O_QKVW, pb + O_QKVB, qkv,
                                                    nullptr, (int)T, 768, 256, 0,
                                                    nullptr, nullptr);
    // windowed MHA (MFMA): 16384 units / 4 waves per block
    attn_mfma<<<dim3(4096), 256, 0, stream>>>(qkv, pb + O_RELB, attn_out);
    // x2 = x + reverse(roll(proj(attn_out))) -> d_out
    gemm_mfma<<<dim3(2, T / 128), 256, 0, stream>>>(attn_out, pb + O_PROJW, pb + O_PROJB,
                                                    d_out, d_in[0], (int)T, 256, 256, 1,
                                                    flag, flag);
    // LN2
    ln_kernel<<<dim3(T / 4), 256, 0, stream>>>(d_out, pb + O_N2G, pb + O_N2B, x2n, 1, flag);
    // hidden = gelu(x2n @ fc1_w + fc1_b)
    gemm_mfma<<<dim3(8, T / 128), 256, 0, stream>>>(x2n, pb + O_FC1W, pb + O_FC1B, hidden,
                                                    nullptr, (int)T, 1024, 256, 2,
                                                    nullptr, nullptr);
    // out = x2 + hidden @ fc2_w + fc2_b
    gemm_mfma<<<dim3(2, T / 128), 256, 0, stream>>>(hidden, pb + O_FC2W, pb + O_FC2B, d_out,
                                                    d_out, (int)T, 256, 1024, 3,
                                                    nullptr, flag);
}